// Round 1
// baseline (3872.601 us; speedup 1.0000x reference)
//
#include <hip/hip_runtime.h>

// ---------------------------------------------------------------------------
// VolumeAttention: 4 feature levels x 6 decoder depths, B=4, NQ=100, C=256, H=8
// Round 1: correctness-first fp32 implementation.
//  - LN gamma/beta folded into ca_wq/ca_wk/ca_wv weights (per depth, once)
//  - per-token LN stats precomputed; normalization fused into KV GEMM staging
//  - flash split-K attention shared by self-attn (masked Nk=100) and cross-attn
// ws usage: ~75.7 MB (floats)
// ---------------------------------------------------------------------------

#define DI __device__ __forceinline__

// ws offsets in floats
constexpr long O_KV    = 0;                       // [21760][512] per-view K|V
constexpr long O_QBUF  = O_KV    + 21760L * 512;  // [16*100][256] current q
constexpr long O_QKV   = O_QBUF  + 409600;        // [1600][768] self-attn qkv
constexpr long O_QSA   = O_QKV   + 1228800;       // [1600][256] q after self-attn
constexpr long O_QHAT  = O_QSA   + 409600;        // [1600][256] LN(q_sa) no-affine
constexpr long O_QN    = O_QHAT  + 409600;        // [1600][256] q-projection
constexpr long O_SAO   = O_QN    + 409600;        // [1600][256] self-attn mha out
constexpr long O_OCA   = O_SAO   + 409600;        // [2][1600][256] cross mha out
constexpr long O_Q12   = O_OCA   + 819200;        // [2][1600][256] q1|q2
constexpr long O_WKV   = O_Q12   + 819200;        // [6][256][512] folded Wk|Wv
constexpr long O_WQ    = O_WKV   + 786432;        // [6][256][256] folded Wq
constexpr long O_BKV   = O_WQ    + 393216;        // [6][512]
constexpr long O_BQ    = O_BKV   + 3072;          // [6][256]
constexpr long O_PO    = O_BQ    + 1536;          // [384][100*32] flash partial O
constexpr long O_PM    = O_PO    + 1228800;       // [384][128] partial max
constexpr long O_PL    = O_PM    + 49152;         // [384][128] partial sum
constexpr long O_MS    = O_PL    + 49152;         // [16][128][128] match scores
constexpr long O_RST   = O_MS    + 262144;        // [4][16][128] row/col stats
constexpr long O_STATS = O_RST   + 8192;          // [43520][2] token mean/rstd
constexpr long WS_FLOATS = O_STATS + 87040;       // ~75.7 MB

DI int sel4(int4 v, int i) { return i == 0 ? v.x : (i == 1 ? v.y : (i == 2 ? v.z : v.w)); }
DI float dot4(float4 a, float4 b) {
  float s = a.x * b.x;
  s = fmaf(a.y, b.y, s); s = fmaf(a.z, b.z, s); s = fmaf(a.w, b.w, s);
  return s;
}

// --- fold LN affine into projection weights -------------------------------
__global__ void fold_w_kernel(const float* __restrict__ ng, const float* __restrict__ wk,
                              const float* __restrict__ wv, const float* __restrict__ wq,
                              float* __restrict__ wkvo, float* __restrict__ wqo) {
  int idx = blockIdx.x * 256 + threadIdx.x;
  const int T1 = 6 * 256 * 512;
  if (idx < T1) {
    int d = idx / (256 * 512); int r = idx % (256 * 512); int c = r / 512; int n = r % 512;
    float g = ng[d * 256 + c];
    float w = (n < 256) ? wk[(d * 256 + c) * 256 + n] : wv[(d * 256 + c) * 256 + (n - 256)];
    wkvo[idx] = g * w;
  } else {
    int j = idx - T1;
    if (j < 6 * 256 * 256) {
      int d = j / 65536; int r = j % 65536; int c = r / 256; int n = r % 256;
      wqo[j] = ng[d * 256 + c] * wq[(d * 256 + c) * 256 + n];
    }
  }
}

__global__ void fold_b_kernel(const float* __restrict__ nb, const float* __restrict__ wk,
                              const float* __restrict__ wv, const float* __restrict__ wq,
                              float* __restrict__ bkvo, float* __restrict__ bqo) {
  int idx = blockIdx.x * 256 + threadIdx.x;
  if (idx >= 6 * 768) return;
  int d = idx / 768, j = idx % 768;
  float s = 0.f;
  if (j < 256) {
    for (int c = 0; c < 256; ++c) s = fmaf(nb[d * 256 + c], wk[(d * 256 + c) * 256 + j], s);
    bkvo[d * 512 + j] = s;
  } else if (j < 512) {
    int n = j - 256;
    for (int c = 0; c < 256; ++c) s = fmaf(nb[d * 256 + c], wv[(d * 256 + c) * 256 + n], s);
    bkvo[d * 512 + j] = s;
  } else {
    int n = j - 512;
    for (int c = 0; c < 256; ++c) s = fmaf(nb[d * 256 + c], wq[(d * 256 + c) * 256 + n], s);
    bqo[d * 256 + n] = s;
  }
}

// --- per-token LN statistics of feature maps ------------------------------
// feat: [B][256][HW]; one block handles 64 tokens of one b.
__global__ __launch_bounds__(256) void ln_stats_kernel(const float* __restrict__ feat,
                                                       float* __restrict__ stats,
                                                       int rowBase, int HW) {
  __shared__ float sred[4][64];
  __shared__ float qred[4][64];
  int b = blockIdx.y, t0 = blockIdx.x * 64;
  int tx = threadIdx.x & 63, ty = threadIdx.x >> 6;
  const float* fb = feat + (long)b * 256 * HW;
  float s = 0.f, q = 0.f;
  for (int k = 0; k < 64; ++k) {
    int c = ty * 64 + k;
    float v = fb[(long)c * HW + t0 + tx];
    s += v; q += v * v;
  }
  sred[ty][tx] = s; qred[ty][tx] = q;
  __syncthreads();
  if (ty == 0) {
    float ts = sred[0][tx] + sred[1][tx] + sred[2][tx] + sred[3][tx];
    float tq = qred[0][tx] + qred[1][tx] + qred[2][tx] + qred[3][tx];
    float m = ts * (1.f / 256.f);
    float var = tq * (1.f / 256.f) - m * m;
    int row = rowBase + b * HW + t0 + tx;
    stats[row * 2 + 0] = m;
    stats[row * 2 + 1] = rsqrtf(var + 1e-5f);
  }
}

// --- init q = broadcast(query_embed) --------------------------------------
__global__ void init_q_kernel(const float* __restrict__ qe, float* __restrict__ qb) {
  int idx = blockIdx.x * 256 + threadIdx.x;
  if (idx < 1600 * 256) {
    int row = idx >> 8, c = idx & 255;
    qb[idx] = qe[(row % 100) * 256 + c];
  }
}

// --- generic GEMM: C[M,N] = A[M,256] @ W[256,N] (+bias) -------------------
// grid (N/64, M/64), 256 threads, 4x4 micro-tile.
__global__ __launch_bounds__(256) void gemm256_kernel(const float* __restrict__ A,
                                                      const float* __restrict__ W,
                                                      const float* __restrict__ bias,
                                                      float* __restrict__ Co, int M, int N) {
  __shared__ float As[32][68];
  __shared__ float Ws[32][68];
  int tid = threadIdx.x;
  int tm = tid & 15, tn = tid >> 4;
  int m0 = blockIdx.y * 64, n0 = blockIdx.x * 64;
  float acc[4][4] = {};
  for (int kt = 0; kt < 8; ++kt) {
    __syncthreads();
#pragma unroll
    for (int it = 0; it < 2; ++it) {
      int i = tid + it * 256;
      int r = i >> 3, c4 = (i & 7) * 4;
      float4 f = *(const float4*)&A[(long)(m0 + r) * 256 + kt * 32 + c4];
      As[c4 + 0][r] = f.x; As[c4 + 1][r] = f.y; As[c4 + 2][r] = f.z; As[c4 + 3][r] = f.w;
    }
#pragma unroll
    for (int it = 0; it < 2; ++it) {
      int i = tid + it * 256;
      int r = i >> 4, c4 = (i & 15) * 4;
      *(float4*)&Ws[r][c4] = *(const float4*)&W[(long)(kt * 32 + r) * N + n0 + c4];
    }
    __syncthreads();
#pragma unroll
    for (int k = 0; k < 32; ++k) {
      float4 a4 = *(const float4*)&As[k][4 * tm];
      float4 b4 = *(const float4*)&Ws[k][4 * tn];
      float av[4] = {a4.x, a4.y, a4.z, a4.w};
      float bv[4] = {b4.x, b4.y, b4.z, b4.w};
#pragma unroll
      for (int i = 0; i < 4; ++i)
#pragma unroll
        for (int j = 0; j < 4; ++j) acc[i][j] = fmaf(av[i], bv[j], acc[i][j]);
    }
  }
  float bv4[4] = {0.f, 0.f, 0.f, 0.f};
  if (bias) {
#pragma unroll
    for (int j = 0; j < 4; ++j) bv4[j] = bias[n0 + 4 * tn + j];
  }
#pragma unroll
  for (int i = 0; i < 4; ++i) {
    int row = m0 + 4 * tm + i;
    float4 o;
    o.x = acc[i][0] + bv4[0]; o.y = acc[i][1] + bv4[1];
    o.z = acc[i][2] + bv4[2]; o.w = acc[i][3] + bv4[3];
    *(float4*)&Co[(long)row * N + n0 + 4 * tn] = o;
  }
}

// --- KV GEMM with fused LN: KV[r,n] = LNhat(tok[r]) @ Wkv' + bkv' ---------
// A rows come straight from feat [B][256][HW] (token-transposed during staging).
// grid (8, 340): N = 512, M = 21760 (one view).
__global__ __launch_bounds__(256) void gemm_kv_kernel(const float* __restrict__ f0,
                                                      const float* __restrict__ f1,
                                                      const float* __restrict__ f2,
                                                      const float* __restrict__ f3,
                                                      const float* __restrict__ stats, int vbase,
                                                      const float* __restrict__ W,
                                                      const float* __restrict__ bias,
                                                      float* __restrict__ Co) {
  __shared__ float As[32][68];
  __shared__ float Ws[32][68];
  __shared__ float sm[64], sr[64];
  int tid = threadIdx.x;
  int m0 = blockIdx.y * 64, n0 = blockIdx.x * 64;
  const float* fp; int HW, rel;
  if (m0 < 16384)      { fp = f0; HW = 4096; rel = m0; }
  else if (m0 < 20480) { fp = f1; HW = 1024; rel = m0 - 16384; }
  else if (m0 < 21504) { fp = f2; HW = 256;  rel = m0 - 20480; }
  else                 { fp = f3; HW = 64;   rel = m0 - 21504; }
  int b = rel / HW;
  int t0 = rel % HW;
  const float* fb = fp + (long)b * 256 * HW;
  if (tid < 64) {
    sm[tid] = stats[(vbase + m0 + tid) * 2 + 0];
    sr[tid] = stats[(vbase + m0 + tid) * 2 + 1];
  }
  int tm = tid & 15, tn = tid >> 4;
  float acc[4][4] = {};
  for (int kt = 0; kt < 8; ++kt) {
    __syncthreads();
#pragma unroll
    for (int it = 0; it < 2; ++it) {
      int i = tid + it * 256;
      int k = i >> 4, c4 = (i & 15) * 4;
      float4 f = *(const float4*)&fb[(long)(kt * 32 + k) * HW + t0 + c4];
      float4 o;
      o.x = (f.x - sm[c4 + 0]) * sr[c4 + 0];
      o.y = (f.y - sm[c4 + 1]) * sr[c4 + 1];
      o.z = (f.z - sm[c4 + 2]) * sr[c4 + 2];
      o.w = (f.w - sm[c4 + 3]) * sr[c4 + 3];
      *(float4*)&As[k][c4] = o;
    }
#pragma unroll
    for (int it = 0; it < 2; ++it) {
      int i = tid + it * 256;
      int r = i >> 4, c4 = (i & 15) * 4;
      *(float4*)&Ws[r][c4] = *(const float4*)&W[(long)(kt * 32 + r) * 512 + n0 + c4];
    }
    __syncthreads();
#pragma unroll
    for (int k = 0; k < 32; ++k) {
      float4 a4 = *(const float4*)&As[k][4 * tm];
      float4 b4 = *(const float4*)&Ws[k][4 * tn];
      float av[4] = {a4.x, a4.y, a4.z, a4.w};
      float bv[4] = {b4.x, b4.y, b4.z, b4.w};
#pragma unroll
      for (int i = 0; i < 4; ++i)
#pragma unroll
        for (int j = 0; j < 4; ++j) acc[i][j] = fmaf(av[i], bv[j], acc[i][j]);
    }
  }
  float bv4[4];
#pragma unroll
  for (int j = 0; j < 4; ++j) bv4[j] = bias[n0 + 4 * tn + j];
#pragma unroll
  for (int i = 0; i < 4; ++i) {
    int row = m0 + 4 * tm + i;
    float4 o;
    o.x = acc[i][0] + bv4[0]; o.y = acc[i][1] + bv4[1];
    o.z = acc[i][2] + bv4[2]; o.w = acc[i][3] + bv4[3];
    *(float4*)&Co[(long)row * 512 + n0 + 4 * tn] = o;
  }
}

// --- row LayerNorm (no affine) for q rows ---------------------------------
__global__ __launch_bounds__(256) void row_ln_kernel(const float* __restrict__ in,
                                                     float* __restrict__ out) {
  __shared__ float s1[4], s2[4];
  long r = blockIdx.x;
  float x = in[r * 256 + threadIdx.x];
  float vs = x, vq = x * x;
  for (int o = 32; o; o >>= 1) { vs += __shfl_xor(vs, o); vq += __shfl_xor(vq, o); }
  int w = threadIdx.x >> 6;
  if ((threadIdx.x & 63) == 0) { s1[w] = vs; s2[w] = vq; }
  __syncthreads();
  float ts = s1[0] + s1[1] + s1[2] + s1[3];
  float tq = s2[0] + s2[1] + s2[2] + s2[3];
  float m = ts * (1.f / 256.f);
  float var = tq * (1.f / 256.f) - m * m;
  out[r * 256 + threadIdx.x] = (x - m) * rsqrtf(var + 1e-5f);
}

// --- flash split-K attention ----------------------------------------------
// One block = (level, b, head, key-chunk of 512). Q rows padded to 128; lane
// pair (2*qi, 2*qi+1) owns hd halves [0,16) / [16,32) and j halves of each
// 32-key tile; full rows recovered with __shfl_xor(.,1).
__global__ __launch_bounds__(256) void flash_kernel(const float* __restrict__ qp, int qld,
                                                    const float* __restrict__ kb,
                                                    const float* __restrict__ vb, int kvld,
                                                    int4 startv, int4 nchv, int4 nkv,
                                                    int4 koffv, int4 kstrbv,
                                                    float* __restrict__ po,
                                                    float* __restrict__ pm,
                                                    float* __restrict__ pl) {
  __shared__ float Kt[32][36];
  __shared__ float Vt[32][36];
  int bid = blockIdx.x;
  int s1 = startv.y, s2 = startv.z, s3 = startv.w;
  int l = (bid < s1) ? 0 : (bid < s2) ? 1 : (bid < s3) ? 2 : 3;
  int r = bid - sel4(startv, l);
  int nc = sel4(nchv, l);
  int b = r / (8 * nc);
  int h = (r / nc) & 7;
  int ch = r % nc;
  int Nk = sel4(nkv, l);
  int qr0 = (l * 4 + b) * 100;
  int kr0 = sel4(koffv, l) + b * sel4(kstrbv, l);
  int j0 = ch * 512;
  int jn = min(512, Nk - j0);
  int tiles = (jn + 31) >> 5;
  int tid = threadIdx.x;
  int qi = tid >> 1, half = tid & 1, ho = half * 16, jb = half * 16;
  const float SC = 0.17677669529663689f;  // 32^-0.5
  float4 q8[8];
  if (qi < 100) {
    const float* qrow = qp + (long)(qr0 + qi) * qld + h * 32;
#pragma unroll
    for (int k = 0; k < 8; ++k) {
      float4 f = *(const float4*)&qrow[4 * k];
      q8[k] = make_float4(f.x * SC, f.y * SC, f.z * SC, f.w * SC);
    }
  } else {
#pragma unroll
    for (int k = 0; k < 8; ++k) q8[k] = make_float4(0.f, 0.f, 0.f, 0.f);
  }
  float m = -1e30f, lsum = 0.f;
  float o[16];
#pragma unroll
  for (int i = 0; i < 16; ++i) o[i] = 0.f;

  for (int kt = 0; kt < tiles; ++kt) {
    __syncthreads();
    {
      int rr = tid >> 3, c4 = (tid & 7) * 4;
      int jr = kt * 32 + rr;
      float4 kf = make_float4(0.f, 0.f, 0.f, 0.f), vf = kf;
      if (jr < jn) {
        long g = (long)(kr0 + j0 + jr) * kvld + h * 32 + c4;
        kf = *(const float4*)&kb[g];
        vf = *(const float4*)&vb[g];
      }
      *(float4*)&Kt[rr][c4] = kf;
      *(float4*)&Vt[rr][c4] = vf;
    }
    __syncthreads();
    float sv[16];
#pragma unroll
    for (int j = 0; j < 16; ++j) {
      float s = 0.f;
#pragma unroll
      for (int k4 = 0; k4 < 8; ++k4) {
        float4 kv = *(const float4*)&Kt[jb + j][4 * k4];
        s = fmaf(q8[k4].x, kv.x, s); s = fmaf(q8[k4].y, kv.y, s);
        s = fmaf(q8[k4].z, kv.z, s); s = fmaf(q8[k4].w, kv.w, s);
      }
      int jglob = j0 + kt * 32 + jb + j;
      sv[j] = (jglob < Nk) ? s : -1e30f;
    }
    float tmax = sv[0];
#pragma unroll
    for (int j = 1; j < 16; ++j) tmax = fmaxf(tmax, sv[j]);
    tmax = fmaxf(tmax, __shfl_xor(tmax, 1));
    float mnew = fmaxf(m, tmax);
    float scale = __expf(m - mnew);
    float p[16]; float psum = 0.f;
#pragma unroll
    for (int j = 0; j < 16; ++j) {
      int jglob = j0 + kt * 32 + jb + j;
      float e = (jglob < Nk) ? __expf(sv[j] - mnew) : 0.f;
      p[j] = e; psum += e;
    }
    psum += __shfl_xor(psum, 1);
    lsum = lsum * scale + psum;
    m = mnew;
#pragma unroll
    for (int i = 0; i < 16; ++i) o[i] *= scale;
    float pO[16];
#pragma unroll
    for (int j = 0; j < 16; ++j) pO[j] = __shfl_xor(p[j], 1);
    int jbO = jb ^ 16;
#pragma unroll
    for (int j = 0; j < 16; ++j) {
      float pj = p[j];
      const float* vrow = &Vt[jb + j][ho];
#pragma unroll
      for (int k = 0; k < 4; ++k) {
        float4 v4 = *(const float4*)&vrow[4 * k];
        o[4 * k + 0] = fmaf(pj, v4.x, o[4 * k + 0]);
        o[4 * k + 1] = fmaf(pj, v4.y, o[4 * k + 1]);
        o[4 * k + 2] = fmaf(pj, v4.z, o[4 * k + 2]);
        o[4 * k + 3] = fmaf(pj, v4.w, o[4 * k + 3]);
      }
    }
#pragma unroll
    for (int j = 0; j < 16; ++j) {
      float pj = pO[j];
      const float* vrow = &Vt[jbO + j][ho];
#pragma unroll
      for (int k = 0; k < 4; ++k) {
        float4 v4 = *(const float4*)&vrow[4 * k];
        o[4 * k + 0] = fmaf(pj, v4.x, o[4 * k + 0]);
        o[4 * k + 1] = fmaf(pj, v4.y, o[4 * k + 1]);
        o[4 * k + 2] = fmaf(pj, v4.z, o[4 * k + 2]);
        o[4 * k + 3] = fmaf(pj, v4.w, o[4 * k + 3]);
      }
    }
  }
  if (qi < 100) {
    float* pod = po + (long)bid * 3200 + qi * 32 + ho;
#pragma unroll
    for (int k = 0; k < 4; ++k)
      *(float4*)&pod[4 * k] = make_float4(o[4 * k], o[4 * k + 1], o[4 * k + 2], o[4 * k + 3]);
    if (half == 0) { pm[bid * 128 + qi] = m; pl[bid * 128 + qi] = lsum; }
  }
}

// --- combine flash partials ------------------------------------------------
// grid = 128 blocks: (l,b,h) for one view / the SA pass.
__global__ __launch_bounds__(256) void combine_kernel(const float* __restrict__ po,
                                                      const float* __restrict__ pm,
                                                      const float* __restrict__ pl,
                                                      int4 startv, int4 nchv,
                                                      float* __restrict__ outp, int outld) {
  int bid = blockIdx.x;
  int l = bid >> 5, rr = bid & 31, b = rr >> 3, h = rr & 7;
  int nc = sel4(nchv, l);
  int sb = sel4(startv, l) + (b * 8 + h) * nc;
  int qr0 = (l * 4 + b) * 100;
  for (int idx = threadIdx.x; idx < 3200; idx += 256) {
    int qi = idx >> 5, hd = idx & 31;
    float mstar = -1e30f;
    for (int c = 0; c < nc; ++c) mstar = fmaxf(mstar, pm[(sb + c) * 128 + qi]);
    float Lt = 0.f, val = 0.f;
    for (int c = 0; c < nc; ++c) {
      float w = __expf(pm[(sb + c) * 128 + qi] - mstar);
      Lt = fmaf(w, pl[(sb + c) * 128 + qi], Lt);
      val = fmaf(w, po[(long)(sb + c) * 3200 + qi * 32 + hd], val);
    }
    outp[(long)(qr0 + qi) * outld + h * 32 + hd] = val / Lt;
  }
}

// --- ms = q1 @ q2^T, tiled 32x32 ------------------------------------------
// grid (16 lb, 16 tiles), ms stored [lb][128][128].
__global__ __launch_bounds__(256) void fuse_ms_kernel(const float* __restrict__ q1,
                                                      const float* __restrict__ q2,
                                                      float* __restrict__ ms) {
  __shared__ float a[32][132];
  __shared__ float bsh[32][132];
  int lb = blockIdx.x;
  int it = blockIdx.y >> 2, jt = blockIdx.y & 3;
  int tid = threadIdx.x;
  int ti = tid & 15, tj = tid >> 4;
  float acc[2][2] = {};
  for (int chalf = 0; chalf < 2; ++chalf) {
    __syncthreads();
#pragma unroll
    for (int k = 0; k < 4; ++k) {
      int i = tid + k * 256;
      int rr = i >> 5, c4 = (i & 31) * 4;
      int row1 = it * 32 + rr, row2 = jt * 32 + rr;
      float4 fa = make_float4(0.f, 0.f, 0.f, 0.f), fb = fa;
      if (row1 < 100) fa = *(const float4*)&q1[(long)(lb * 100 + row1) * 256 + chalf * 128 + c4];
      if (row2 < 100) fb = *(const float4*)&q2[(long)(lb * 100 + row2) * 256 + chalf * 128 + c4];
      *(float4*)&a[rr][c4] = fa;
      *(float4*)&bsh[rr][c4] = fb;
    }
    __syncthreads();
#pragma unroll
    for (int k4 = 0; k4 < 32; ++k4) {
      float4 a0 = *(const float4*)&a[2 * ti][4 * k4];
      float4 a1 = *(const float4*)&a[2 * ti + 1][4 * k4];
      float4 b0 = *(const float4*)&bsh[2 * tj][4 * k4];
      float4 b1 = *(const float4*)&bsh[2 * tj + 1][4 * k4];
      acc[0][0] += dot4(a0, b0); acc[0][1] += dot4(a0, b1);
      acc[1][0] += dot4(a1, b0); acc[1][1] += dot4(a1, b1);
    }
  }
#pragma unroll
  for (int i = 0; i < 2; ++i)
#pragma unroll
    for (int j = 0; j < 2; ++j)
      ms[(long)(lb * 128 + it * 32 + 2 * ti + i) * 128 + jt * 32 + 2 * tj + j] = acc[i][j];
}

// --- row & column softmax stats of ms -------------------------------------
__global__ void fuse_stats_kernel(const float* __restrict__ ms, float* __restrict__ rst) {
  int lb = blockIdx.x, tid = threadIdx.x;
  if (tid < 100) {
    const float* row = ms + (long)(lb * 128 + tid) * 128;
    float mx = row[0];
    for (int j = 1; j < 100; ++j) mx = fmaxf(mx, row[j]);
    float s = 0.f;
    for (int j = 0; j < 100; ++j) s += __expf(row[j] - mx);
    rst[(0 * 16 + lb) * 128 + tid] = mx;
    rst[(1 * 16 + lb) * 128 + tid] = s;
  } else if (tid >= 128 && tid < 228) {
    int j = tid - 128;
    const float* colp = ms + (long)lb * 128 * 128 + j;
    float mx = colp[0];
    for (int i = 1; i < 100; ++i) mx = fmaxf(mx, colp[i * 128]);
    float s = 0.f;
    for (int i = 0; i < 100; ++i) s += __expf(colp[i * 128] - mx);
    rst[(2 * 16 + lb) * 128 + j] = mx;
    rst[(3 * 16 + lb) * 128 + j] = s;
  }
}

// --- r1/r2 mixing + final channel softmax ---------------------------------
// grid (16 lb, 10 chunks of 10 rows), thread = channel.
__global__ __launch_bounds__(256) void fuse_apply_kernel(const float* __restrict__ ms,
                                                         const float* __restrict__ rst,
                                                         const float* __restrict__ q1,
                                                         const float* __restrict__ q2,
                                                         const float* __restrict__ qsa,
                                                         float* __restrict__ qout) {
  __shared__ float pr[100], pc[100];
  __shared__ float red1[4], red2[4];
  int lb = blockIdx.x, qc = blockIdx.y, tid = threadIdx.x;
  for (int ii = 0; ii < 10; ++ii) {
    int i = qc * 10 + ii;
    long r = lb * 100 + i;
    if (tid < 100) {
      float rm = rst[(0 * 16 + lb) * 128 + i], rs = rst[(1 * 16 + lb) * 128 + i];
      pr[tid] = __expf(ms[(long)(lb * 128 + i) * 128 + tid] - rm) / rs;
    } else if (tid >= 128 && tid < 228) {
      int i2 = tid - 128;
      float cm = rst[(2 * 16 + lb) * 128 + i], cs = rst[(3 * 16 + lb) * 128 + i];
      pc[i2] = __expf(ms[(long)(lb * 128 + i2) * 128 + i] - cm) / cs;
    }
    __syncthreads();
    float acc1 = 0.f, acc2 = 0.f;
    for (int j = 0; j < 100; ++j) acc1 = fmaf(pr[j], q2[(long)(lb * 100 + j) * 256 + tid], acc1);
    for (int j = 0; j < 100; ++j) acc2 = fmaf(pc[j], q1[(long)(lb * 100 + j) * 256 + tid], acc2);
    float z = qsa[r * 256 + tid] + q1[r * 256 + tid] + acc1 + q2[r * 256 + tid] + acc2;
    float v = z;
    for (int off = 32; off; off >>= 1) v = fmaxf(v, __shfl_xor(v, off));
    int w = tid >> 6;
    if ((tid & 63) == 0) red1[w] = v;
    __syncthreads();
    float zm = fmaxf(fmaxf(red1[0], red1[1]), fmaxf(red1[2], red1[3]));
    float e = __expf(z - zm);
    float sv = e;
    for (int off = 32; off; off >>= 1) sv += __shfl_xor(sv, off);
    if ((tid & 63) == 0) red2[w] = sv;
    __syncthreads();
    float es = red2[0] + red2[1] + red2[2] + red2[3];
    qout[r * 256 + tid] = e / es;
    __syncthreads();
  }
}

// ---------------------------------------------------------------------------
extern "C" void kernel_launch(void* const* d_in, const int* in_sizes, int n_in,
                              void* d_out, int out_size, void* d_ws, size_t ws_size,
                              hipStream_t stream) {
  (void)in_sizes; (void)n_in; (void)out_size; (void)ws_size;
  const float* feats[2][4] = {
      {(const float*)d_in[0], (const float*)d_in[1], (const float*)d_in[2], (const float*)d_in[3]},
      {(const float*)d_in[4], (const float*)d_in[5], (const float*)d_in[6], (const float*)d_in[7]}};
  const float* qe   = (const float*)d_in[8];
  const float* ng   = (const float*)d_in[9];
  const float* nb   = (const float*)d_in[10];
  const float* wq   = (const float*)d_in[11];
  const float* wk   = (const float*)d_in[12];
  const float* wv   = (const float*)d_in[13];
  const float* wp   = (const float*)d_in[14];
  const float* bp   = (const float*)d_in[15];
  const float* swqkv= (const float*)d_in[16];
  const float* swp  = (const float*)d_in[17];
  const float* sbp  = (const float*)d_in[18];

  float* ws = (float*)d_ws;
  float* KVp   = ws + O_KV;
  float* QBUFp = ws + O_QBUF;
  float* QKVp  = ws + O_QKV;
  float* QSAp  = ws + O_QSA;
  float* QHATp = ws + O_QHAT;
  float* QNp   = ws + O_QN;
  float* SAOp  = ws + O_SAO;
  float* OCAp  = ws + O_OCA;
  float* Q12p  = ws + O_Q12;
  float* WKVp  = ws + O_WKV;
  float* WQp   = ws + O_WQ;
  float* BKVp  = ws + O_BKV;
  float* BQp   = ws + O_BQ;
  float* POp   = ws + O_PO;
  float* PMp   = ws + O_PM;
  float* PLp   = ws + O_PL;
  float* MSp   = ws + O_MS;
  float* RSTp  = ws + O_RST;
  float* STATSp= ws + O_STATS;

  const int HWs[4] = {4096, 1024, 256, 64};
  const int VOs[4] = {0, 16384, 20480, 21504};

  fold_w_kernel<<<4608, 256, 0, stream>>>(ng, wk, wv, wq, WKVp, WQp);
  fold_b_kernel<<<18, 256, 0, stream>>>(nb, wk, wv, wq, BKVp, BQp);
  for (int v = 0; v < 2; ++v)
    for (int l = 0; l < 4; ++l)
      ln_stats_kernel<<<dim3(HWs[l] / 64, 4), 256, 0, stream>>>(
          feats[v][l], STATSp, v * 21760 + VOs[l], HWs[l]);
  init_q_kernel<<<1600, 256, 0, stream>>>(qe, QBUFp);

  const int4 saStart = make_int4(0, 32, 64, 96);
  const int4 saNch   = make_int4(1, 1, 1, 1);
  const int4 saNk    = make_int4(100, 100, 100, 100);
  const int4 saKoff  = make_int4(0, 400, 800, 1200);
  const int4 saKstrb = make_int4(100, 100, 100, 100);
  const int4 caStart = make_int4(0, 256, 320, 352);
  const int4 caNch   = make_int4(8, 2, 1, 1);
  const int4 caNk    = make_int4(4096, 1024, 256, 64);
  const int4 caKoff  = make_int4(0, 16384, 20480, 21504);
  const int4 caKstrb = make_int4(4096, 1024, 256, 64);

  for (int d = 0; d < 6; ++d) {
    // --- self attention ---
    gemm256_kernel<<<dim3(12, 25), 256, 0, stream>>>(QBUFp, swqkv + (long)d * 196608, nullptr,
                                                     QKVp, 1600, 768);
    flash_kernel<<<128, 256, 0, stream>>>(QKVp, 768, QKVp + 256, QKVp + 512, 768,
                                          saStart, saNch, saNk, saKoff, saKstrb, POp, PMp, PLp);
    combine_kernel<<<128, 256, 0, stream>>>(POp, PMp, PLp, saStart, saNch, SAOp, 256);
    gemm256_kernel<<<dim3(4, 25), 256, 0, stream>>>(SAOp, swp + (long)d * 65536, sbp + d * 256,
                                                    QSAp, 1600, 256);
    // --- cross-attention query projection ---
    row_ln_kernel<<<1600, 256, 0, stream>>>(QSAp, QHATp);
    gemm256_kernel<<<dim3(4, 25), 256, 0, stream>>>(QHATp, WQp + (long)d * 65536, BQp + d * 256,
                                                    QNp, 1600, 256);
    // --- cross attention per view ---
    for (int v = 0; v < 2; ++v) {
      gemm_kv_kernel<<<dim3(8, 340), 256, 0, stream>>>(
          feats[v][0], feats[v][1], feats[v][2], feats[v][3], STATSp, v * 21760,
          WKVp + (long)d * 131072, BKVp + d * 512, KVp);
      flash_kernel<<<384, 256, 0, stream>>>(QNp, 256, KVp, KVp + 256, 512,
                                            caStart, caNch, caNk, caKoff, caKstrb, POp, PMp, PLp);
      combine_kernel<<<128, 256, 0, stream>>>(POp, PMp, PLp, caStart, caNch,
                                              OCAp + (long)v * 409600, 256);
    }
    gemm256_kernel<<<dim3(4, 50), 256, 0, stream>>>(OCAp, wp + (long)d * 65536, bp + d * 256,
                                                    Q12p, 3200, 256);
    // --- matching fusion + channel softmax ---
    fuse_ms_kernel<<<dim3(16, 16), 256, 0, stream>>>(Q12p, Q12p + 409600, MSp);
    fuse_stats_kernel<<<16, 256, 0, stream>>>(MSp, RSTp);
    fuse_apply_kernel<<<dim3(16, 10), 256, 0, stream>>>(MSp, RSTp, Q12p, Q12p + 409600,
                                                        QSAp, QBUFp);
  }
  hipMemcpyAsync(d_out, QBUFp, 409600 * sizeof(float), hipMemcpyDeviceToDevice, stream);
}